// Round 2
// baseline (163.610 us; speedup 1.0000x reference)
//
#include <hip/hip_runtime.h>

// RepulsionXTB: per-pair repulsion energy, segment-summed per molecule.
//
// Inputs (setup_inputs order, harness converts ints to int32):
//   d_in[0] element_idxs  int32  [M*A]   (M=2048, A=64 -> 131072)
//   d_in[1] neighbor_idxs int32  [2*P]   (P=8388608)
//   d_in[2] distances     f32    [P]
//   d_in[3] y_ab          f32    [16]   == outer(y_eff, y_eff)        (separable!)
//   d_in[4] sqrt_alpha_ab f32    [16]   == sqrt(outer(alpha, alpha))  (separable!)
//   d_in[5] k_rep_ab      f32    [16]   == 1.5 everywhere except [0,0]=1.0
// Output: energies f32 [M]

#define AB_D 1.8897261258369282

// ---------------- kernel 1: pack species to 2 bits/atom + zero output -------
__global__ __launch_bounds__(256) void pack_zero_kernel(
    const int* __restrict__ elem, int natoms, int nwords,
    unsigned* __restrict__ packed, float* __restrict__ out, int M)
{
    int g = blockIdx.x * blockDim.x + threadIdx.x;
    if (g < M) out[g] = 0.0f;
    if (packed != nullptr && g < nwords) {
        int base = g * 16;
        unsigned w = 0u;
        if (base + 16 <= natoms) {
            const int4* p = (const int4*)(elem + base);
            #pragma unroll
            for (int q = 0; q < 4; ++q) {
                int4 v = p[q];
                w |= ((unsigned)v.x & 3u) << (2 * (4 * q + 0));
                w |= ((unsigned)v.y & 3u) << (2 * (4 * q + 1));
                w |= ((unsigned)v.z & 3u) << (2 * (4 * q + 2));
                w |= ((unsigned)v.w & 3u) << (2 * (4 * q + 3));
            }
        } else {
            for (int j = 0; j < 16; ++j) {
                int a = base + j;
                unsigned s = (a < natoms) ? ((unsigned)elem[a] & 3u) : 0u;
                w |= s << (2 * j);
            }
        }
        packed[g] = w;
    }
}

// 4-way select by 2-bit index, pure VALU (3 cndmask)
__device__ __forceinline__ float sel4(unsigned s, float a, float b, float c, float d)
{
    float lo = (s & 1u) ? b : a;
    float hi = (s & 1u) ? d : c;
    return (s & 2u) ? hi : lo;
}

// ---------------- kernel 2: main pair loop ----------------------------------
// LDS: [acc: M f32][packed: nwords u32]
__global__ __launch_bounds__(512, 6) void rep_main_kernel(
    const int* __restrict__ nbr, const float* __restrict__ dist,
    const unsigned* __restrict__ packed_g,
    const float* __restrict__ y_ab, const float* __restrict__ sa_ab,
    const float* __restrict__ kr_ab,
    long long P, int M, int nwords, int ashift, int A,
    float* __restrict__ partials, float* __restrict__ out,
    int mode /*0 = write partial row, 1 = global atomics*/)
{
    extern __shared__ char smem[];
    float* acc = (float*)smem;
    size_t acc_bytes = ((size_t)M * 4 + 255) & ~(size_t)255;
    unsigned* pk = (unsigned*)(smem + acc_bytes);

    const int tid = threadIdx.x;
    const int nthr = blockDim.x;

    for (int m = tid; m < M; m += nthr) acc[m] = 0.0f;
    for (int w = tid; w < nwords; w += nthr) pk[w] = packed_g[w];

    // per-species constants from table diagonals (tables are outer products)
    const float yv0 = sqrtf(y_ab[0]),  yv1 = sqrtf(y_ab[5]);
    const float yv2 = sqrtf(y_ab[10]), yv3 = sqrtf(y_ab[15]);
    const float av0 = sqrtf(sa_ab[0]),  av1 = sqrtf(sa_ab[5]);
    const float av2 = sqrtf(sa_ab[10]), av3 = sqrtf(sa_ab[15]);
    const float krHH = kr_ab[0];   // H-H
    const float krXX = kr_ab[5];   // everything else
    __syncthreads();

    const float ABf   = (float)AB_D;
    const float RC    = (float)(5.2 * AB_D);
    const float RCINV = (float)(1.0 / (5.2 * AB_D));
    const int* nb0 = nbr;
    const int* nb1 = nbr + P;

    auto process = [&](int a0, int a1, float draw) {
        float d = fmaxf(draw, 1e-7f) * ABf;
        if (d < RC) {
            unsigned ua0 = (unsigned)a0, ua1 = (unsigned)a1;
            unsigned w0 = pk[ua0 >> 4];
            unsigned w1 = pk[ua1 >> 4];
            unsigned s0 = (w0 >> ((ua0 & 15u) * 2u)) & 3u;
            unsigned s1 = (w1 >> ((ua1 & 15u) * 2u)) & 3u;

            float y  = sel4(s0, yv0, yv1, yv2, yv3) * sel4(s1, yv0, yv1, yv2, yv3);
            float sa = sel4(s0, av0, av1, av2, av3) * sel4(s1, av0, av1, av2, av3);
            float kr = ((s0 | s1) == 0u) ? krHH : krXX;

            float drep = __powf(d, kr);                       // log2+mul+exp2
            float x    = d * RCINV;
            float om   = fmaf(-x, x, 1.0f);
            float e    = 1.0f - __builtin_amdgcn_rcpf(fmaxf(om, 1e-10f));
            float rep  = y * __builtin_amdgcn_rcpf(d) * __expf(fmaf(-sa, drep, e));

            unsigned mol = (ashift >= 0) ? (ua0 >> ashift) : (ua0 / (unsigned)A);
            atomicAdd(&acc[mol], rep);
        }
    };

    long long P4 = P >> 2;
    long long gstride = (long long)gridDim.x * nthr;
    for (long long q = (long long)blockIdx.x * nthr + tid; q < P4; q += gstride) {
        int4   i0 = ((const int4*)nb0)[q];
        int4   i1 = ((const int4*)nb1)[q];
        float4 dv = ((const float4*)dist)[q];
        process(i0.x, i1.x, dv.x);
        process(i0.y, i1.y, dv.y);
        process(i0.z, i1.z, dv.z);
        process(i0.w, i1.w, dv.w);
    }
    // tail (P not divisible by 4) — handled by block 0 (empty for P=8.4M)
    long long tail0 = P4 << 2;
    if (blockIdx.x == 0) {
        for (long long p = tail0 + tid; p < P; p += nthr)
            process(nb0[p], nb1[p], dist[p]);
    }
    __syncthreads();

    if (mode == 0) {
        float* row = partials + (size_t)blockIdx.x * (size_t)M;
        for (int m = tid; m < M; m += nthr) row[m] = acc[m];
    } else {
        for (int m = tid; m < M; m += nthr) {
            float v = acc[m];
            if (v != 0.0f) atomicAdd(&out[m], v);
        }
    }
}

// ---------------- kernel 3: column-sum the partial rows ---------------------
__global__ __launch_bounds__(256) void reduce_kernel(
    const float* __restrict__ partials, float* __restrict__ out,
    int M, int nblk, int rows_per)
{
    int m = blockIdx.x * blockDim.x + threadIdx.x;
    if (m >= M) return;
    int r0 = blockIdx.y * rows_per;
    int r1 = r0 + rows_per;
    if (r1 > nblk) r1 = nblk;
    if (r0 >= r1) return;
    float s0 = 0.f, s1 = 0.f, s2 = 0.f, s3 = 0.f;
    int r = r0;
    for (; r + 3 < r1; r += 4) {
        s0 += partials[(size_t)(r + 0) * M + m];
        s1 += partials[(size_t)(r + 1) * M + m];
        s2 += partials[(size_t)(r + 2) * M + m];
        s3 += partials[(size_t)(r + 3) * M + m];
    }
    for (; r < r1; ++r) s0 += partials[(size_t)r * M + m];
    atomicAdd(&out[m], (s0 + s1) + (s2 + s3));
}

extern "C" void kernel_launch(void* const* d_in, const int* in_sizes, int n_in,
                              void* d_out, int out_size, void* d_ws, size_t ws_size,
                              hipStream_t stream)
{
    const int*   elem  = (const int*)d_in[0];
    const int*   nbr   = (const int*)d_in[1];
    const float* dist  = (const float*)d_in[2];
    const float* y_ab  = (const float*)d_in[3];
    const float* sa_ab = (const float*)d_in[4];
    const float* kr_ab = (const float*)d_in[5];
    float* out = (float*)d_out;

    const int natoms = in_sizes[0];
    const long long P = (long long)in_sizes[2];
    const int M = out_size;
    const int A = natoms / M;
    int ashift = -1;
    if (A > 0 && (A & (A - 1)) == 0) {
        int s = 0;
        while ((1 << s) < A) ++s;
        ashift = s;
    }
    const int nwords = (natoms + 15) / 16;

    // workspace layout: [packed: nwords u32 (256B aligned)][partials: nblk*M f32]
    size_t packed_bytes = ((size_t)nwords * 4 + 255) & ~(size_t)255;
    bool have_packed = (ws_size >= packed_bytes);
    unsigned* packed = have_packed ? (unsigned*)d_ws : nullptr;
    if (!have_packed) return;  // harness always provides workspace

    const int BLOCK = 512;
    int nblk = 768;            // 3 blocks/CU on 256 CUs
    float* partials = nullptr;
    int mode = 1;              // global-atomic fallback
    {
        size_t avail = ws_size - packed_bytes;
        size_t rowb = (size_t)M * 4;
        long long maxrows = (long long)(avail / rowb);
        if (maxrows >= 64) {
            nblk = (int)(maxrows < 768 ? maxrows : 768);
            partials = (float*)((char*)d_ws + packed_bytes);
            mode = 0;
        }
    }

    // kernel 1: pack + zero out
    {
        int total = (nwords > M) ? nwords : M;
        int g = (total + 255) / 256;
        hipLaunchKernelGGL(pack_zero_kernel, dim3(g), dim3(256), 0, stream,
                           elem, natoms, nwords, packed, out, M);
    }

    // kernel 2: main
    {
        size_t acc_bytes = ((size_t)M * 4 + 255) & ~(size_t)255;
        size_t smem = acc_bytes + (size_t)nwords * 4;
        hipLaunchKernelGGL(rep_main_kernel, dim3(nblk), dim3(BLOCK), smem, stream,
                           nbr, dist, packed, y_ab, sa_ab, kr_ab,
                           P, M, nwords, ashift, A, partials, out, mode);
    }

    // kernel 3: reduce partial rows
    if (mode == 0) {
        const int SPLIT = 32;
        int rows_per = (nblk + SPLIT - 1) / SPLIT;
        dim3 grid((M + 255) / 256, SPLIT);
        hipLaunchKernelGGL(reduce_kernel, grid, dim3(256), 0, stream,
                           partials, out, M, nblk, rows_per);
    }
}

// Round 3
// 154.016 us; speedup vs baseline: 1.0623x; 1.0623x over previous
//
#include <hip/hip_runtime.h>

// RepulsionXTB: per-pair repulsion energy, segment-summed per molecule.
//
// Inputs (setup_inputs order, harness converts ints to int32):
//   d_in[0] element_idxs  int32  [M*A]   (M=2048, A=64 -> 131072)
//   d_in[1] neighbor_idxs int32  [2*P]   (P=8388608)
//   d_in[2] distances     f32    [P]
//   d_in[3] y_ab          f32    [16]
//   d_in[4] sqrt_alpha_ab f32    [16]
//   d_in[5] k_rep_ab      f32    [16]   (1.5 everywhere except [0,0]=1.0)
// Output: energies f32 [M]
//
// R3 notes: __powf == full ocml pow on HIP (R2 regression) -> replaced by
// sqrt-select since kr in {1.0,1.5}; HH flag carried in sign of table sa.
// 16-entry float2 LDS table: each entry spans 2 unique banks, same-entry
// lanes broadcast -> conflict-free ds_read_b64.

#define AB_D 1.8897261258369282
#define L2E  1.4426950408889634f   // log2(e)

// ---------------- kernel 1: pack species to 2 bits/atom + zero output -------
__global__ __launch_bounds__(256) void pack_zero_kernel(
    const int* __restrict__ elem, int natoms, int nwords,
    unsigned* __restrict__ packed, float* __restrict__ out, int M)
{
    int g = blockIdx.x * blockDim.x + threadIdx.x;
    if (g < M) out[g] = 0.0f;
    if (packed != nullptr && g < nwords) {
        int base = g * 16;
        unsigned w = 0u;
        if (base + 16 <= natoms) {
            const int4* p = (const int4*)(elem + base);
            #pragma unroll
            for (int q = 0; q < 4; ++q) {
                int4 v = p[q];
                w |= ((unsigned)v.x & 3u) << (2 * (4 * q + 0));
                w |= ((unsigned)v.y & 3u) << (2 * (4 * q + 1));
                w |= ((unsigned)v.z & 3u) << (2 * (4 * q + 2));
                w |= ((unsigned)v.w & 3u) << (2 * (4 * q + 3));
            }
        } else {
            for (int j = 0; j < 16; ++j) {
                int a = base + j;
                unsigned s = (a < natoms) ? ((unsigned)elem[a] & 3u) : 0u;
                w |= s << (2 * j);
            }
        }
        packed[g] = w;
    }
}

// ---------------- kernel 2: main pair loop ----------------------------------
// LDS layout: [acc: M f32][tbl: 16 float2][pk: nwords u32]
__global__ __launch_bounds__(1024, 8) void rep_main_kernel(
    const int* __restrict__ nbr, const float* __restrict__ dist,
    const unsigned* __restrict__ packed_g,
    const float* __restrict__ y_ab, const float* __restrict__ sa_ab,
    const float* __restrict__ kr_ab,
    long long P, int M, int nwords, int ashift, int A,
    float* __restrict__ partials, float* __restrict__ out,
    int mode /*0 = write partial row, 1 = global atomics*/)
{
    extern __shared__ char smem[];
    float*  acc = (float*)smem;
    float2* tbl = (float2*)(smem + (size_t)M * 4);
    unsigned* pk = (unsigned*)(smem + (size_t)M * 4 + 16 * sizeof(float2));

    const int tid = threadIdx.x;
    const int nthr = blockDim.x;

    for (int m = tid; m < M; m += nthr) acc[m] = 0.0f;
    for (int w = tid; w < nwords; w += nthr) pk[w] = packed_g[w];
    if (tid < 16) {
        float sa = sa_ab[tid] * L2E;           // pre-scale for exp2
        if (kr_ab[tid] == 1.0f) sa = -sa;      // sign bit encodes kr==1 (H-H)
        tbl[tid] = make_float2(y_ab[tid], sa);
    }
    __syncthreads();

    const float ABf    = (float)AB_D;
    const float DMIN   = (float)(1e-7 * AB_D);
    const float RC     = (float)(5.2 * AB_D);
    const float RCINV  = (float)(1.0 / (5.2 * AB_D));
    const int* nb0 = nbr;
    const int* nb1 = nbr + P;

    auto process = [&](int a0, int a1, float draw) {
        float d = fmaxf(draw * ABf, DMIN);
        if (d < RC) {
            unsigned ua0 = (unsigned)a0, ua1 = (unsigned)a1;
            unsigned w0 = pk[ua0 >> 4];
            unsigned w1 = pk[ua1 >> 4];
            unsigned s0 = (w0 >> ((ua0 & 15u) * 2u)) & 3u;
            unsigned s1 = (w1 >> ((ua1 & 15u) * 2u)) & 3u;
            float2 t = tbl[s0 * 4u + s1];      // x = y, y = ±sa*log2e

            float sq   = __builtin_amdgcn_sqrtf(d);
            float fac  = (t.y < 0.0f) ? 1.0f : sq;     // kr==1 ? d : d^1.5
            float drep = d * fac;
            float x    = d * RCINV;
            float om   = fmaf(-x, x, 1.0f);            // >= 0 inside cutoff
            float r    = __builtin_amdgcn_rcpf(om);    // om==0 -> +inf -> exp2(-inf)=0
            float e    = fmaf(-L2E, r, L2E);           // log2e*(1 - 1/om)
            float arg  = fmaf(-fabsf(t.y), drep, e);
            float ex   = __builtin_amdgcn_exp2f(arg);
            float rep  = t.x * __builtin_amdgcn_rcpf(d) * ex;

            unsigned mol = (ashift >= 0) ? (ua0 >> ashift) : (ua0 / (unsigned)A);
            atomicAdd(&acc[mol], rep);
        }
    };

    long long P4 = P >> 2;
    long long gstride = (long long)gridDim.x * nthr;
    for (long long q = (long long)blockIdx.x * nthr + tid; q < P4; q += gstride) {
        int4   i0 = ((const int4*)nb0)[q];
        int4   i1 = ((const int4*)nb1)[q];
        float4 dv = ((const float4*)dist)[q];
        process(i0.x, i1.x, dv.x);
        process(i0.y, i1.y, dv.y);
        process(i0.z, i1.z, dv.z);
        process(i0.w, i1.w, dv.w);
    }
    // tail (P not divisible by 4) — handled by block 0 (empty for P=8.4M)
    long long tail0 = P4 << 2;
    if (blockIdx.x == 0) {
        for (long long p = tail0 + tid; p < P; p += nthr)
            process(nb0[p], nb1[p], dist[p]);
    }
    __syncthreads();

    if (mode == 0) {
        float* row = partials + (size_t)blockIdx.x * (size_t)M;
        for (int m = tid; m < M; m += nthr) row[m] = acc[m];
    } else {
        for (int m = tid; m < M; m += nthr) {
            float v = acc[m];
            if (v != 0.0f) atomicAdd(&out[m], v);
        }
    }
}

// ---------------- kernel 3: column-sum the partial rows ---------------------
__global__ __launch_bounds__(256) void reduce_kernel(
    const float* __restrict__ partials, float* __restrict__ out,
    int M, int nblk, int rows_per)
{
    int m = blockIdx.x * blockDim.x + threadIdx.x;
    if (m >= M) return;
    int r0 = blockIdx.y * rows_per;
    int r1 = r0 + rows_per;
    if (r1 > nblk) r1 = nblk;
    if (r0 >= r1) return;
    float s0 = 0.f, s1 = 0.f, s2 = 0.f, s3 = 0.f;
    int r = r0;
    for (; r + 3 < r1; r += 4) {
        s0 += partials[(size_t)(r + 0) * M + m];
        s1 += partials[(size_t)(r + 1) * M + m];
        s2 += partials[(size_t)(r + 2) * M + m];
        s3 += partials[(size_t)(r + 3) * M + m];
    }
    for (; r < r1; ++r) s0 += partials[(size_t)r * M + m];
    atomicAdd(&out[m], (s0 + s1) + (s2 + s3));
}

extern "C" void kernel_launch(void* const* d_in, const int* in_sizes, int n_in,
                              void* d_out, int out_size, void* d_ws, size_t ws_size,
                              hipStream_t stream)
{
    const int*   elem  = (const int*)d_in[0];
    const int*   nbr   = (const int*)d_in[1];
    const float* dist  = (const float*)d_in[2];
    const float* y_ab  = (const float*)d_in[3];
    const float* sa_ab = (const float*)d_in[4];
    const float* kr_ab = (const float*)d_in[5];
    float* out = (float*)d_out;

    const int natoms = in_sizes[0];
    const long long P = (long long)in_sizes[2];
    const int M = out_size;
    const int A = natoms / M;
    int ashift = -1;
    if (A > 0 && (A & (A - 1)) == 0) {
        int s = 0;
        while ((1 << s) < A) ++s;
        ashift = s;
    }
    const int nwords = (natoms + 15) / 16;

    // workspace layout: [packed: nwords u32 (256B aligned)][partials: nblk*M f32]
    size_t packed_bytes = ((size_t)nwords * 4 + 255) & ~(size_t)255;
    bool have_packed = (ws_size >= packed_bytes);
    unsigned* packed = have_packed ? (unsigned*)d_ws : nullptr;
    if (!have_packed) return;  // harness always provides workspace

    const int BLOCK = 1024;
    int nblk = 512;            // 2 blocks/CU on 256 CUs -> 32 waves/CU
    float* partials = nullptr;
    int mode = 1;              // global-atomic fallback
    {
        size_t avail = ws_size - packed_bytes;
        size_t rowb = (size_t)M * 4;
        long long maxrows = (long long)(avail / rowb);
        if (maxrows >= 64) {
            nblk = (int)(maxrows < 512 ? maxrows : 512);
            partials = (float*)((char*)d_ws + packed_bytes);
            mode = 0;
        }
    }

    // kernel 1: pack + zero out
    {
        int total = (nwords > M) ? nwords : M;
        int g = (total + 255) / 256;
        hipLaunchKernelGGL(pack_zero_kernel, dim3(g), dim3(256), 0, stream,
                           elem, natoms, nwords, packed, out, M);
    }

    // kernel 2: main
    {
        size_t smem = (size_t)M * 4 + 16 * sizeof(float2) + (size_t)nwords * 4;
        hipLaunchKernelGGL(rep_main_kernel, dim3(nblk), dim3(BLOCK), smem, stream,
                           nbr, dist, packed, y_ab, sa_ab, kr_ab,
                           P, M, nwords, ashift, A, partials, out, mode);
    }

    // kernel 3: reduce partial rows
    if (mode == 0) {
        const int SPLIT = 32;
        int rows_per = (nblk + SPLIT - 1) / SPLIT;
        dim3 grid((M + 255) / 256, SPLIT);
        hipLaunchKernelGGL(reduce_kernel, grid, dim3(256), 0, stream,
                           partials, out, M, nblk, rows_per);
    }
}